// Round 6
// baseline (1368.333 us; speedup 1.0000x reference)
//
#include <hip/hip_runtime.h>
#include <math.h>

// ---------------------------------------------------------------------------
// SiameseGNN_GIN: GIN(x1) & GIN(x2) -> cdist -> sort-pool(k=50 by last col)
// -> fc1+LN+ReLU -> fc2+LN+ReLU -> fc3+sigmoid
// Key restructure: (x+agg)@W = x@W + A*(x@W)  => aggregate AFTER the linear.
// CSR (by dst) gather instead of atomics. Distance matrix never materialized.
// R2: two-phase LDS top-k. R3: k-split fc1. R4: gather pipelining + fused
// gemm23. R5: gemm23 LDS 58.5->47.2 KB + conflict-free ht writes.
// R6: gemm23 two-half stage2 (ht 34.8->16.9 KB, LDS 28.8 KB -> 5 blocks/CU;
// occupancy was the 177us story) + graph1/graph2 batched into one node array
// (same weights; kills the tiny-dispatch tail) + 8-deep agg gather.
// ---------------------------------------------------------------------------

#define CPB 64   // chunk-blocks per graph in top-k phase A
#define FKS 64   // k-split chunks for fc1

// ---------------- CSR build ----------------
__global__ __launch_bounds__(256) void hist_kernel(const int* __restrict__ dst, int E,
                                                   int* __restrict__ counts, int base) {
    int e = blockIdx.x * 256 + threadIdx.x;
    if (e < E) atomicAdd(&counts[dst[e] + base], 1);
}

__global__ __launch_bounds__(256) void chunksum_kernel(const int* __restrict__ in, int total,
                                                       int* __restrict__ bsum) {
    __shared__ int red[256];
    int t = threadIdx.x;
    int base = blockIdx.x * 1024 + t * 4;
    int s = 0;
#pragma unroll
    for (int j = 0; j < 4; ++j) { int i = base + j; if (i < total) s += in[i]; }
    red[t] = s; __syncthreads();
    for (int off = 128; off; off >>= 1) { if (t < off) red[t] += red[t + off]; __syncthreads(); }
    if (t == 0) bsum[blockIdx.x] = red[0];
}

// exclusive scan of 1024-chunks; chunk base from baseArr (or 0). Optionally dup to out2.
__global__ __launch_bounds__(256) void scanchunk_kernel(const int* __restrict__ in, int total,
                                                        const int* __restrict__ baseArr,
                                                        int* __restrict__ out,
                                                        int* __restrict__ out2) {
    __shared__ int tsum[256];
    int t = threadIdx.x;
    int base_i = blockIdx.x * 1024 + t * 4;
    int v[4];
#pragma unroll
    for (int j = 0; j < 4; ++j) v[j] = (base_i + j < total) ? in[base_i + j] : 0;
    int l0 = 0, l1 = v[0], l2 = v[0] + v[1], l3 = l2 + v[2];
    int s = l3 + v[3];
    tsum[t] = s; __syncthreads();
    for (int off = 1; off < 256; off <<= 1) {
        int x = (t >= off) ? tsum[t - off] : 0;
        __syncthreads();
        tsum[t] += x;
        __syncthreads();
    }
    int cb = baseArr ? baseArr[blockIdx.x] : 0;
    int te = cb + tsum[t] - s;
    int outs[4] = { te + l0, te + l1, te + l2, te + l3 };
#pragma unroll
    for (int j = 0; j < 4; ++j) {
        int i = base_i + j;
        if (i < total) { out[i] = outs[j]; if (out2) out2[i] = outs[j]; }
    }
}

__global__ __launch_bounds__(256) void fill_kernel(const int* __restrict__ src,
                                                   const int* __restrict__ dst, int E,
                                                   int* __restrict__ cur, int* __restrict__ csr,
                                                   int base) {
    int e = blockIdx.x * 256 + threadIdx.x;
    if (e < E) {
        int d = dst[e] + base;
        int p = atomicAdd(&cur[d], 1);
        csr[p] = src[e] + base;
    }
}

// ---------------- fp32 GEMM: Y[N,KO] = relu?(X[N,KI] @ W[KI,KO] + bias?) ----------------
template <int KI, int KO, bool BIAS, bool RELU>
__global__ __launch_bounds__(256) void gemm_kernel(const float* __restrict__ X,
                                                   const float* __restrict__ Wm,
                                                   const float* __restrict__ bias,
                                                   float* __restrict__ Y, int N) {
    constexpr int TPR = KO / 4;       // threads across columns (float4 cols)
    constexpr int RPT = KO / 16;      // rows per thread (8 for KO=128, 4 for KO=64)
    constexpr int XS = 68;            // 64 rows + 4 pad (keeps 16B alignment)
    __shared__ __align__(16) float wl[32 * KO];
    __shared__ __align__(16) float xt[32 * XS];
    const int t = threadIdx.x;
    const int r0 = blockIdx.x * 64;
    const int tx = t % TPR, ty = t / TPR;
    float4 acc[RPT];
#pragma unroll
    for (int r = 0; r < RPT; ++r) acc[r] = make_float4(0.f, 0.f, 0.f, 0.f);

    for (int kb = 0; kb < KI; kb += 32) {
        __syncthreads();
#pragma unroll
        for (int i = t; i < 32 * KO / 4; i += 256)
            ((float4*)wl)[i] = ((const float4*)Wm)[kb * KO / 4 + i];
#pragma unroll
        for (int L = t; L < 512; L += 256) {
            int row = L >> 3, kq = L & 7;
            int gr = r0 + row;
            float4 v = make_float4(0.f, 0.f, 0.f, 0.f);
            if (gr < N) v = *(const float4*)(X + (size_t)gr * KI + kb + kq * 4);
            xt[(kq * 4 + 0) * XS + row] = v.x;
            xt[(kq * 4 + 1) * XS + row] = v.y;
            xt[(kq * 4 + 2) * XS + row] = v.z;
            xt[(kq * 4 + 3) * XS + row] = v.w;
        }
        __syncthreads();
#pragma unroll
        for (int k = 0; k < 32; ++k) {
            float4 wv = ((const float4*)wl)[k * TPR + tx];
            const float4* xp = (const float4*)(xt + k * XS + ty * RPT);
#pragma unroll
            for (int rq = 0; rq < RPT / 4; ++rq) {
                float4 xv = xp[rq];
                acc[rq*4+0].x += xv.x * wv.x; acc[rq*4+0].y += xv.x * wv.y;
                acc[rq*4+0].z += xv.x * wv.z; acc[rq*4+0].w += xv.x * wv.w;
                acc[rq*4+1].x += xv.y * wv.x; acc[rq*4+1].y += xv.y * wv.y;
                acc[rq*4+1].z += xv.y * wv.z; acc[rq*4+1].w += xv.y * wv.w;
                acc[rq*4+2].x += xv.z * wv.x; acc[rq*4+2].y += xv.z * wv.y;
                acc[rq*4+2].z += xv.z * wv.z; acc[rq*4+2].w += xv.z * wv.w;
                acc[rq*4+3].x += xv.w * wv.x; acc[rq*4+3].y += xv.w * wv.y;
                acc[rq*4+3].z += xv.w * wv.z; acc[rq*4+3].w += xv.w * wv.w;
            }
        }
    }
    float4 b4 = make_float4(0.f, 0.f, 0.f, 0.f);
    if (BIAS) b4 = ((const float4*)bias)[tx];
#pragma unroll
    for (int r = 0; r < RPT; ++r) {
        int gr = r0 + ty * RPT + r;
        if (gr < N) {
            float4 o = make_float4(acc[r].x + b4.x, acc[r].y + b4.y,
                                   acc[r].z + b4.z, acc[r].w + b4.w);
            if (RELU) {
                o.x = fmaxf(o.x, 0.f); o.y = fmaxf(o.y, 0.f);
                o.z = fmaxf(o.z, 0.f); o.w = fmaxf(o.w, 0.f);
            }
            *(float4*)(Y + (size_t)gr * KO + tx * 4) = o;
        }
    }
}

// ---- fused conv: Y[N,64] = ( relu(X[N,128] @ W1 + b1) ) @ W2, W2: [128,64] ----------
// R6: stage2 runs in two 64-hcol halves so ht is half-size; LDS 28.8 KB -> 5 blocks/CU.
__global__ __launch_bounds__(256) void gemm23_kernel(const float* __restrict__ X,
                                                     const float* __restrict__ W1,
                                                     const float* __restrict__ b1,
                                                     const float* __restrict__ W2,
                                                     float* __restrict__ Y, int N) {
    __shared__ __align__(16) float wl[32 * 64];    // 8 KB: W1 16k-tiles / W2 32k-tiles
    __shared__ __align__(16) float xt[16 * 68];    // 4.25 KB: X^T [k][row+pad]
    __shared__ __align__(16) float ht[64 * 66];    // 16.5 KB: half of H^T [col][row], stride 66
    const int t = threadIdx.x;
    const int r0 = blockIdx.x * 64;

    // ---- stage 1: H = relu(X @ W1 + b1), all 128 cols kept in registers ----
    // mapping: tx in [0,32) -> rows {2tx, 2tx+1}; ty in [0,8) -> cols [16ty,16ty+16)
    const int tx = t & 31, ty = t >> 5;
    float acc[2][16];
#pragma unroll
    for (int r = 0; r < 2; ++r)
#pragma unroll
        for (int c = 0; c < 16; ++c) acc[r][c] = 0.f;

    for (int kb = 0; kb < 128; kb += 16) {
        __syncthreads();
        // W1 tile: rows kb..kb+16, all 128 cols = 512 float4
#pragma unroll
        for (int i = t; i < 512; i += 256)
            ((float4*)wl)[i] = ((const float4*)W1)[kb * 32 + i];
        // X tile transposed: 64 rows x 16 k
        {
            int row = t >> 2, kq = t & 3;
            int gr = r0 + row;
            float4 v = make_float4(0.f, 0.f, 0.f, 0.f);
            if (gr < N) v = *(const float4*)(X + (size_t)gr * 128 + kb + kq * 4);
            xt[(kq * 4 + 0) * 68 + row] = v.x;
            xt[(kq * 4 + 1) * 68 + row] = v.y;
            xt[(kq * 4 + 2) * 68 + row] = v.z;
            xt[(kq * 4 + 3) * 68 + row] = v.w;
        }
        __syncthreads();
#pragma unroll
        for (int kk = 0; kk < 16; ++kk) {
            float2 xv = *(const float2*)(xt + kk * 68 + tx * 2);
            const float4* wp = (const float4*)(wl + kk * 128 + ty * 16);
#pragma unroll
            for (int cq = 0; cq < 4; ++cq) {
                float4 wv = wp[cq];
                acc[0][cq*4+0] += xv.x * wv.x; acc[0][cq*4+1] += xv.x * wv.y;
                acc[0][cq*4+2] += xv.x * wv.z; acc[0][cq*4+3] += xv.x * wv.w;
                acc[1][cq*4+0] += xv.y * wv.x; acc[1][cq*4+1] += xv.y * wv.y;
                acc[1][cq*4+2] += xv.y * wv.z; acc[1][cq*4+3] += xv.y * wv.w;
            }
        }
    }

    // ---- stage 2 in two 64-hcol halves: Y = H @ W2 (128 -> 64) ----
    const int tx2 = t & 15, ty2 = t >> 4;          // 16 f4-cols, 16 groups x 4 rows
    float4 acc2[4];
#pragma unroll
    for (int r = 0; r < 4; ++r) acc2[r] = make_float4(0.f, 0.f, 0.f, 0.f);

    for (int half = 0; half < 2; ++half) {
        __syncthreads();            // prior ht/wl readers done
        if ((ty >> 2) == half) {    // this thread's 16 cols belong to this half
            // bias + relu -> ht[col_local][row]; float2 at 2tx -> cheap
#pragma unroll
            for (int cq = 0; cq < 4; ++cq) {
                float4 b4 = ((const float4*)b1)[ty * 4 + cq];
                float bb[4] = { b4.x, b4.y, b4.z, b4.w };
#pragma unroll
                for (int j = 0; j < 4; ++j) {
                    int col_local = (ty & 3) * 16 + cq * 4 + j;   // 0..63
                    float2 o;
                    o.x = fmaxf(acc[0][cq*4+j] + bb[j], 0.f);
                    o.y = fmaxf(acc[1][cq*4+j] + bb[j], 0.f);
                    *(float2*)(ht + col_local * 66 + tx * 2) = o;
                }
            }
        }
        for (int kb = 0; kb < 2; ++kb) {
            __syncthreads();        // ht writes visible (kb=0); wl readers done (kb=1)
            // W2 rows half*64 + kb*32 .. +32, 64 cols = 512 float4
#pragma unroll
            for (int i = t; i < 512; i += 256)
                ((float4*)wl)[i] = ((const float4*)W2)[(half * 64 + kb * 32) * 16 + i];
            __syncthreads();
#pragma unroll
            for (int k = 0; k < 32; ++k) {
                float4 wv = ((const float4*)wl)[k * 16 + tx2];
                float4 xv = *(const float4*)(ht + (kb * 32 + k) * 66 + ty2 * 4);
                acc2[0].x += xv.x * wv.x; acc2[0].y += xv.x * wv.y;
                acc2[0].z += xv.x * wv.z; acc2[0].w += xv.x * wv.w;
                acc2[1].x += xv.y * wv.x; acc2[1].y += xv.y * wv.y;
                acc2[1].z += xv.y * wv.z; acc2[1].w += xv.y * wv.w;
                acc2[2].x += xv.z * wv.x; acc2[2].y += xv.z * wv.y;
                acc2[2].z += xv.z * wv.z; acc2[2].w += xv.z * wv.w;
                acc2[3].x += xv.w * wv.x; acc2[3].y += xv.w * wv.y;
                acc2[3].z += xv.w * wv.z; acc2[3].w += xv.w * wv.w;
            }
        }
    }
#pragma unroll
    for (int r = 0; r < 4; ++r) {
        int gr = r0 + ty2 * 4 + r;
        if (gr < N) *(float4*)(Y + (size_t)gr * 64 + tx2 * 4) = acc2[r];
    }
}

// ---------------- aggregation: out[n] = relu(x[n] + sum_{e:dst=n} x[src] + bias) -------
// R6: 8-deep gather pipeline + 4-deep remainder, dual accumulators.
template <int VEC>  // float4s per row: 32 (width 128) or 16 (width 64)
__global__ __launch_bounds__(256) void agg_kernel(const float* __restrict__ x,
                                                  const int* __restrict__ rs,
                                                  const int* __restrict__ csr,
                                                  const float* __restrict__ bias,
                                                  float* __restrict__ out, int N) {
    const int NPB = 256 / VEC;
    const int t = threadIdx.x;
    const int node = blockIdx.x * NPB + t / VEC;
    const int c = t % VEC;
    if (node >= N) return;
    const float4* xb = (const float4*)x;
    float4 a0 = xb[(size_t)node * VEC + c];
    float4 a1 = make_float4(0.f, 0.f, 0.f, 0.f);
    int k = rs[node];
    const int s1 = rs[node + 1];
    for (; k + 8 <= s1; k += 8) {
        int i0 = csr[k], i1 = csr[k+1], i2 = csr[k+2], i3 = csr[k+3];
        int i4 = csr[k+4], i5 = csr[k+5], i6 = csr[k+6], i7 = csr[k+7];
        float4 v0 = xb[(size_t)i0 * VEC + c];
        float4 v1 = xb[(size_t)i1 * VEC + c];
        float4 v2 = xb[(size_t)i2 * VEC + c];
        float4 v3 = xb[(size_t)i3 * VEC + c];
        float4 v4 = xb[(size_t)i4 * VEC + c];
        float4 v5 = xb[(size_t)i5 * VEC + c];
        float4 v6 = xb[(size_t)i6 * VEC + c];
        float4 v7 = xb[(size_t)i7 * VEC + c];
        a0.x += v0.x; a0.y += v0.y; a0.z += v0.z; a0.w += v0.w;
        a1.x += v1.x; a1.y += v1.y; a1.z += v1.z; a1.w += v1.w;
        a0.x += v2.x; a0.y += v2.y; a0.z += v2.z; a0.w += v2.w;
        a1.x += v3.x; a1.y += v3.y; a1.z += v3.z; a1.w += v3.w;
        a0.x += v4.x; a0.y += v4.y; a0.z += v4.z; a0.w += v4.w;
        a1.x += v5.x; a1.y += v5.y; a1.z += v5.z; a1.w += v5.w;
        a0.x += v6.x; a0.y += v6.y; a0.z += v6.z; a0.w += v6.w;
        a1.x += v7.x; a1.y += v7.y; a1.z += v7.z; a1.w += v7.w;
    }
    if (k + 4 <= s1) {
        int i0 = csr[k], i1 = csr[k+1], i2 = csr[k+2], i3 = csr[k+3];
        float4 v0 = xb[(size_t)i0 * VEC + c];
        float4 v1 = xb[(size_t)i1 * VEC + c];
        float4 v2 = xb[(size_t)i2 * VEC + c];
        float4 v3 = xb[(size_t)i3 * VEC + c];
        a0.x += v0.x; a0.y += v0.y; a0.z += v0.z; a0.w += v0.w;
        a1.x += v1.x; a1.y += v1.y; a1.z += v1.z; a1.w += v1.w;
        a0.x += v2.x; a0.y += v2.y; a0.z += v2.z; a0.w += v2.w;
        a1.x += v3.x; a1.y += v3.y; a1.z += v3.z; a1.w += v3.w;
        k += 4;
    }
    for (; k < s1; ++k) {
        int i = csr[k];
        float4 v = xb[(size_t)i * VEC + c];
        a0.x += v.x; a0.y += v.y; a0.z += v.z; a0.w += v.w;
    }
    float4 b4 = ((const float4*)bias)[c];
    float4 o;
    o.x = fmaxf(a0.x + a1.x + b4.x, 0.f);
    o.y = fmaxf(a0.y + a1.y + b4.y, 0.f);
    o.z = fmaxf(a0.z + a1.z + b4.z, 0.f);
    o.w = fmaxf(a0.w + a1.w + b4.w, 0.f);
    ((float4*)out)[(size_t)node * VEC + c] = o;
}

// ---------------- scores: d(out1[n], out2[198]) via cdist formula, fp64 ----------------
__global__ __launch_bounds__(256) void scores_kernel(const float* __restrict__ out1,
                                                     const float* __restrict__ out2,
                                                     double* __restrict__ sc, int N) {
    const int t = threadIdx.x;
    const int node = blockIdx.x * 4 + (t >> 6);
    const int lane = t & 63;
    if (node >= N) return;
    float a = out1[(size_t)node * 64 + lane];
    float bv = out2[198 * 64 + lane];
    double na = (double)a * a;
    double nb = (double)bv * bv;
    double dd = (double)a * bv;
    for (int off = 32; off; off >>= 1) {
        na += __shfl_xor(na, off);
        nb += __shfl_xor(nb, off);
        dd += __shfl_xor(dd, off);
    }
    if (lane == 0) {
        double sq = na + nb - 2.0 * dd;
        sc[node] = (sq > 0.0) ? sqrt(sq) : 0.0;
    }
}

// ---------------- top-50 phase A: per-chunk top-50 into candidate list -----------------
__global__ __launch_bounds__(256) void topkA_kernel(const double* __restrict__ sc,
                                                    double* __restrict__ cv,
                                                    int* __restrict__ ci, int npg) {
    const int g = blockIdx.x / CPB, cb = blockIdx.x % CPB;
    const int chunk = (npg + CPB - 1) / CPB;
    const int base = cb * chunk;
    const int len = (npg - base < chunk) ? (npg - base) : chunk;
    const int t = threadIdx.x;
    __shared__ double lv[400];
    __shared__ double wvs[4];
    __shared__ int wss[4];
    const double* s = sc + (size_t)g * npg;
    for (int i = t; i < chunk; i += 256)
        lv[i] = (i < len) ? s[base + i] : -1.0e300;
    __syncthreads();
    const int ob = (g * CPB + cb) * 50;
    for (int r = 0; r < 50; ++r) {
        double bv = -1.0e300; int bs = 0x3fffffff;
        for (int i = t; i < chunk; i += 256) {
            double v = lv[i];
            if (v > bv || (v == bv && i < bs)) { bv = v; bs = i; }
        }
#pragma unroll
        for (int off = 32; off; off >>= 1) {
            double ov = __shfl_xor(bv, off);
            int os = __shfl_xor(bs, off);
            if (ov > bv || (ov == bv && os < bs)) { bv = ov; bs = os; }
        }
        if ((t & 63) == 0) { wvs[t >> 6] = bv; wss[t >> 6] = bs; }
        __syncthreads();
        if (t == 0) {
#pragma unroll
            for (int w = 1; w < 4; ++w)
                if (wvs[w] > bv || (wvs[w] == bv && wss[w] < bs)) { bv = wvs[w]; bs = wss[w]; }
            cv[ob + r] = bv;
            ci[ob + r] = base + bs;
            lv[bs] = -1.0e300;
        }
        __syncthreads();
    }
}

// ---------------- top-50 phase B: top-50 of CPB*50 candidates per graph ----------------
__global__ __launch_bounds__(256) void topkB_kernel(const double* __restrict__ cv,
                                                    const int* __restrict__ ci,
                                                    int* __restrict__ topk) {
    const int g = blockIdx.x, t = threadIdx.x;
    const int M = CPB * 50;   // 3200
    __shared__ double lv[CPB * 50];
    __shared__ int li[CPB * 50];
    __shared__ double wvs[4];
    __shared__ int wis[4], wss[4];
    for (int i = t; i < M; i += 256) {
        lv[i] = cv[(size_t)g * M + i];
        li[i] = ci[(size_t)g * M + i];
    }
    __syncthreads();
    for (int r = 0; r < 50; ++r) {
        double bv = -1.0e300; int bi = 0x3fffffff, bs = 0;
        for (int i = t; i < M; i += 256) {
            double v = lv[i]; int idx = li[i];
            if (v > bv || (v == bv && idx < bi)) { bv = v; bi = idx; bs = i; }
        }
#pragma unroll
        for (int off = 32; off; off >>= 1) {
            double ov = __shfl_xor(bv, off);
            int oi = __shfl_xor(bi, off);
            int os = __shfl_xor(bs, off);
            if (ov > bv || (ov == bv && oi < bi)) { bv = ov; bi = oi; bs = os; }
        }
        if ((t & 63) == 0) { wvs[t >> 6] = bv; wis[t >> 6] = bi; wss[t >> 6] = bs; }
        __syncthreads();
        if (t == 0) {
#pragma unroll
            for (int w = 1; w < 4; ++w)
                if (wvs[w] > bv || (wvs[w] == bv && wis[w] < bi)) {
                    bv = wvs[w]; bi = wis[w]; bs = wss[w];
                }
            topk[g * 50 + r] = bi;
            lv[bs] = -1.0e300;
        }
        __syncthreads();
    }
}

// ---------------- pooled rows: d(out1[sel], out2[j]) for 400 rows x 199 cols -----------
__global__ __launch_bounds__(256) void pooled_kernel(const float* __restrict__ out1,
                                                     const float* __restrict__ out2,
                                                     const int* __restrict__ topk,
                                                     float* __restrict__ pooled, int npg) {
    const int bk = blockIdx.x;           // 0..399
    const int g = bk / 50, kk = bk % 50;
    __shared__ float arow[64];
    const int t = threadIdx.x;
    const int node = g * npg + topk[g * 50 + kk];
    if (t < 64) arow[t] = out1[(size_t)node * 64 + t];
    __syncthreads();
    if (t < 199) {
        double na = 0.0, nb = 0.0, dd = 0.0;
        for (int k2 = 0; k2 < 64; ++k2) {
            double a = arow[k2];
            double b = out2[t * 64 + k2];
            na += a * a; nb += b * b; dd += a * b;
        }
        double sq = na + nb - 2.0 * dd;
        pooled[(size_t)g * 9950 + kk * 199 + t] = (float)((sq > 0.0) ? sqrt(sq) : 0.0);
    }
}

// ---------------- fc1 k-split: part[b,ks,f] = sum over chunk ks of p[i]*W[i,f] --------
__global__ __launch_bounds__(256) void fc1_partial_kernel(const float* __restrict__ pooled,
                                                          const float* __restrict__ W,
                                                          double* __restrict__ part) {
    const int b = blockIdx.x >> 6;        // / FKS
    const int ks = blockIdx.x & (FKS - 1);
    const int t = threadIdx.x;
    const int f = t & 127, half = t >> 7;
    const int C = (9950 + FKS - 1) / FKS; // 156
    const int i0 = ks * C;
    const int i1 = (i0 + C < 9950) ? (i0 + C) : 9950;
    const float* p = pooled + (size_t)b * 9950;
    double acc = 0.0;
    for (int i = i0 + half; i < i1; i += 2)
        acc += (double)p[i] * (double)W[(size_t)i * 128 + f];
    __shared__ double red[256];
    red[t] = acc; __syncthreads();
    if (half == 0)
        part[((size_t)b * FKS + ks) * 128 + f] = red[f] + red[128 + f];
}

__global__ __launch_bounds__(128) void fc1_reduce_kernel(const double* __restrict__ part,
                                                         const float* __restrict__ bias,
                                                         float* __restrict__ z1) {
    const int b = blockIdx.x, f = threadIdx.x;
    double acc = 0.0;
    for (int ks = 0; ks < FKS; ++ks)
        acc += part[((size_t)b * FKS + ks) * 128 + f];
    z1[b * 128 + f] = (float)(acc + (double)bias[f]);
}

// ---------------- head: LN+ReLU, fc2, LN+ReLU, fc3, sigmoid ---------------------------
__global__ __launch_bounds__(128) void head_kernel(const float* __restrict__ z1,
                                                   const float* __restrict__ g1,
                                                   const float* __restrict__ be1,
                                                   const float* __restrict__ W2,
                                                   const float* __restrict__ b2,
                                                   const float* __restrict__ g2,
                                                   const float* __restrict__ be2,
                                                   const float* __restrict__ W3,
                                                   const float* __restrict__ b3,
                                                   float* __restrict__ out) {
    const int b = blockIdx.x, t = threadIdx.x;
    __shared__ double red[128];
    __shared__ float shy[128];
    __shared__ float sh2[64];
    float z = z1[b * 128 + t];
    red[t] = z; __syncthreads();
    for (int off = 64; off; off >>= 1) { if (t < off) red[t] += red[t + off]; __syncthreads(); }
    double mu = red[0] / 128.0; __syncthreads();
    double dv = (double)z - mu;
    red[t] = dv * dv; __syncthreads();
    for (int off = 64; off; off >>= 1) { if (t < off) red[t] += red[t + off]; __syncthreads(); }
    double var = red[0] / 128.0; __syncthreads();
    float y = (float)(dv / sqrt(var + 1e-5)) * g1[t] + be1[t];
    shy[t] = fmaxf(y, 0.f); __syncthreads();
    double a2 = 0.0;
    if (t < 64) {
        for (int i = 0; i < 128; ++i) a2 += (double)shy[i] * (double)W2[i * 64 + t];
        a2 += (double)b2[t];
    }
    red[t] = (t < 64) ? a2 : 0.0; __syncthreads();
    for (int off = 64; off; off >>= 1) { if (t < off) red[t] += red[t + off]; __syncthreads(); }
    double mu2 = red[0] / 64.0; __syncthreads();
    double dv2 = a2 - mu2;
    red[t] = (t < 64) ? dv2 * dv2 : 0.0; __syncthreads();
    for (int off = 64; off; off >>= 1) { if (t < off) red[t] += red[t + off]; __syncthreads(); }
    double var2 = red[0] / 64.0; __syncthreads();
    if (t < 64) {
        float h2 = (float)(dv2 / sqrt(var2 + 1e-5)) * g2[t] + be2[t];
        sh2[t] = fmaxf(h2, 0.f);
    }
    __syncthreads();
    red[t] = (t < 64) ? (double)sh2[t] * (double)W3[t] : 0.0; __syncthreads();
    for (int off = 64; off; off >>= 1) { if (t < off) red[t] += red[t + off]; __syncthreads(); }
    if (t == 0) {
        double zf = red[0] + (double)b3[0];
        out[b] = (float)(1.0 / (1.0 + exp(-zf)));
    }
}

// ---------------------------------------------------------------------------
extern "C" void kernel_launch(void* const* d_in, const int* in_sizes, int n_in,
                              void* d_out, int out_size, void* d_ws, size_t ws_size,
                              hipStream_t stream) {
    (void)n_in; (void)out_size; (void)ws_size;
    const float* x1  = (const float*)d_in[0];
    const int*   ei1 = (const int*)d_in[1];
    const float* x2  = (const float*)d_in[3];
    const int*   ei2 = (const int*)d_in[4];
    const float* W1a = (const float*)d_in[5];
    const float* b1a = (const float*)d_in[6];
    const float* W1b = (const float*)d_in[7];
    const float* b1b = (const float*)d_in[8];
    const float* W2a = (const float*)d_in[9];
    const float* b2a = (const float*)d_in[10];
    const float* W2b = (const float*)d_in[11];
    const float* b2b = (const float*)d_in[12];
    const float* f1W = (const float*)d_in[13];
    const float* f1b = (const float*)d_in[14];
    const float* g1  = (const float*)d_in[15];
    const float* be1 = (const float*)d_in[16];
    const float* f2W = (const float*)d_in[17];
    const float* f2b = (const float*)d_in[18];
    const float* g2  = (const float*)d_in[19];
    const float* be2 = (const float*)d_in[20];
    const float* f3W = (const float*)d_in[21];
    const float* f3b = (const float*)d_in[22];
    float* out = (float*)d_out;

    const int n1 = in_sizes[0] / 128;     // 200000
    const int e1 = in_sizes[1] / 2;       // 2000000
    const int n2 = in_sizes[3] / 128;     // 199
    const int e2 = in_sizes[4] / 2;       // 3184
    const int npg = n1 / 8;               // 25000
    const int n  = n1 + n2;               // combined node count
    const int et = e1 + e2;

    // workspace carve-up
    char* p = (char*)d_ws;
    auto alloc = [&](size_t bytes) { char* r = p; p += (bytes + 255) & ~(size_t)255; return r; };
    float*  A    = (float*)alloc((size_t)n * 128 * 4);
    float*  Bb   = (float*)alloc((size_t)n * 128 * 4);
    double* sc   = (double*)alloc((size_t)n1 * 8);
    int*    rs   = (int*)alloc((size_t)(n + 1) * 4);    // counts -> row_start (in place)
    int*    cur  = (int*)alloc((size_t)(n + 1) * 4);
    int*    csr  = (int*)alloc((size_t)et * 4);
    int*    bsum = (int*)alloc(4096);
    double* cndv = (double*)alloc((size_t)8 * CPB * 50 * 8);
    int*    cndi = (int*)alloc((size_t)8 * CPB * 50 * 4);
    int*    tk   = (int*)alloc(8 * 50 * 4);
    float*  pld  = (float*)alloc((size_t)8 * 9950 * 4);
    double* f1p  = (double*)alloc((size_t)8 * FKS * 128 * 8);
    float*  z1   = (float*)alloc(8 * 128 * 4);

    const int* src1 = ei1;           const int* dst1 = ei1 + e1;
    const int* src2 = ei2;           const int* dst2 = ei2 + e2;

    // ---- combined CSR build (graph2 nodes appended after graph1's n1) ----
    hipMemsetAsync(rs, 0, (size_t)(n + 1) * 4, stream);
    hist_kernel<<<(e1 + 255) / 256, 256, 0, stream>>>(dst1, e1, rs, 0);
    hist_kernel<<<(e2 + 255) / 256, 256, 0, stream>>>(dst2, e2, rs, n1);
    int tot = n + 1, nch = (tot + 1023) / 1024;
    chunksum_kernel<<<nch, 256, 0, stream>>>(rs, tot, bsum);
    scanchunk_kernel<<<1, 256, 0, stream>>>(bsum, nch, nullptr, bsum, nullptr);
    scanchunk_kernel<<<nch, 256, 0, stream>>>(rs, tot, bsum, rs, cur);
    fill_kernel<<<(e1 + 255) / 256, 256, 0, stream>>>(src1, dst1, e1, cur, csr, 0);
    fill_kernel<<<(e2 + 255) / 256, 256, 0, stream>>>(src2, dst2, e2, cur, csr, n1);

    // ---- GIN on combined node set (shared weights) ----
    int gb  = (n + 63) / 64;
    int gb1 = (n1 + 63) / 64;
    int gb2 = (n2 + 63) / 64;
    gemm_kernel<128, 128, false, false><<<gb1, 256, 0, stream>>>(x1, W1a, nullptr, A, n1);
    gemm_kernel<128, 128, false, false><<<gb2, 256, 0, stream>>>(x2, W1a, nullptr,
                                                                 A + (size_t)n1 * 128, n2);
    agg_kernel<32><<<(n + 7) / 8, 256, 0, stream>>>(A, rs, csr, b1a, Bb, n);
    gemm23_kernel<<<gb, 256, 0, stream>>>(Bb, W1b, b1b, W2a, A, n);      // A = h@W2a [n,64]
    agg_kernel<16><<<(n + 15) / 16, 256, 0, stream>>>(A, rs, csr, b2a, Bb, n);
    gemm_kernel<64, 64, true, true><<<gb, 256, 0, stream>>>(Bb, W2b, b2b, A, n);  // out = A

    const float* out1 = A;
    const float* o2   = A + (size_t)n1 * 64;

    // ---- scores -> two-phase top-50 per graph -> pooled rows ----
    scores_kernel<<<(n1 + 3) / 4, 256, 0, stream>>>(out1, o2, sc, n1);
    topkA_kernel<<<8 * CPB, 256, 0, stream>>>(sc, cndv, cndi, npg);
    topkB_kernel<<<8, 256, 0, stream>>>(cndv, cndi, tk);
    pooled_kernel<<<400, 256, 0, stream>>>(out1, o2, tk, pld, npg);

    // ---- head ----
    fc1_partial_kernel<<<8 * FKS, 256, 0, stream>>>(pld, f1W, f1p);
    fc1_reduce_kernel<<<8, 128, 0, stream>>>(f1p, f1b, z1);
    head_kernel<<<8, 128, 0, stream>>>(z1, g1, be1, f2W, f2b, g2, be2, f3W, f3b, out);
}

// Round 7
// 1241.711 us; speedup vs baseline: 1.1020x; 1.1020x over previous
//
#include <hip/hip_runtime.h>
#include <math.h>

// ---------------------------------------------------------------------------
// SiameseGNN_GIN: GIN(x1) & GIN(x2) -> cdist -> sort-pool(k=50 by last col)
// -> fc1+LN+ReLU -> fc2+LN+ReLU -> fc3+sigmoid
// Key restructure: (x+agg)@W = x@W + A*(x@W)  => aggregate AFTER the linear.
// CSR (by dst) gather instead of atomics. Distance matrix never materialized.
// R2: two-phase LDS top-k. R3: k-split fc1. R4: gather pipelining + fused
// gemm23. R5: gemm23 LDS 47.2 KB + conflict-free ht writes (177us, VGPR 72).
// R6: batched graphs + 8-deep agg (kept); two-half gemm23 REGRESSED
// (314us: VGPR 72->164 binds occupancy at 11%, misaligned stride-66 reads).
// R7: revert gemm23 to the R5 structure; keep batching + 8-deep agg.
// ---------------------------------------------------------------------------

#define CPB 64   // chunk-blocks per graph in top-k phase A
#define FKS 64   // k-split chunks for fc1

// ---------------- CSR build ----------------
__global__ __launch_bounds__(256) void hist_kernel(const int* __restrict__ dst, int E,
                                                   int* __restrict__ counts, int base) {
    int e = blockIdx.x * 256 + threadIdx.x;
    if (e < E) atomicAdd(&counts[dst[e] + base], 1);
}

__global__ __launch_bounds__(256) void chunksum_kernel(const int* __restrict__ in, int total,
                                                       int* __restrict__ bsum) {
    __shared__ int red[256];
    int t = threadIdx.x;
    int base = blockIdx.x * 1024 + t * 4;
    int s = 0;
#pragma unroll
    for (int j = 0; j < 4; ++j) { int i = base + j; if (i < total) s += in[i]; }
    red[t] = s; __syncthreads();
    for (int off = 128; off; off >>= 1) { if (t < off) red[t] += red[t + off]; __syncthreads(); }
    if (t == 0) bsum[blockIdx.x] = red[0];
}

// exclusive scan of 1024-chunks; chunk base from baseArr (or 0). Optionally dup to out2.
__global__ __launch_bounds__(256) void scanchunk_kernel(const int* __restrict__ in, int total,
                                                        const int* __restrict__ baseArr,
                                                        int* __restrict__ out,
                                                        int* __restrict__ out2) {
    __shared__ int tsum[256];
    int t = threadIdx.x;
    int base_i = blockIdx.x * 1024 + t * 4;
    int v[4];
#pragma unroll
    for (int j = 0; j < 4; ++j) v[j] = (base_i + j < total) ? in[base_i + j] : 0;
    int l0 = 0, l1 = v[0], l2 = v[0] + v[1], l3 = l2 + v[2];
    int s = l3 + v[3];
    tsum[t] = s; __syncthreads();
    for (int off = 1; off < 256; off <<= 1) {
        int x = (t >= off) ? tsum[t - off] : 0;
        __syncthreads();
        tsum[t] += x;
        __syncthreads();
    }
    int cb = baseArr ? baseArr[blockIdx.x] : 0;
    int te = cb + tsum[t] - s;
    int outs[4] = { te + l0, te + l1, te + l2, te + l3 };
#pragma unroll
    for (int j = 0; j < 4; ++j) {
        int i = base_i + j;
        if (i < total) { out[i] = outs[j]; if (out2) out2[i] = outs[j]; }
    }
}

__global__ __launch_bounds__(256) void fill_kernel(const int* __restrict__ src,
                                                   const int* __restrict__ dst, int E,
                                                   int* __restrict__ cur, int* __restrict__ csr,
                                                   int base) {
    int e = blockIdx.x * 256 + threadIdx.x;
    if (e < E) {
        int d = dst[e] + base;
        int p = atomicAdd(&cur[d], 1);
        csr[p] = src[e] + base;
    }
}

// ---------------- fp32 GEMM: Y[N,KO] = relu?(X[N,KI] @ W[KI,KO] + bias?) ----------------
template <int KI, int KO, bool BIAS, bool RELU>
__global__ __launch_bounds__(256) void gemm_kernel(const float* __restrict__ X,
                                                   const float* __restrict__ Wm,
                                                   const float* __restrict__ bias,
                                                   float* __restrict__ Y, int N) {
    constexpr int TPR = KO / 4;       // threads across columns (float4 cols)
    constexpr int RPT = KO / 16;      // rows per thread (8 for KO=128, 4 for KO=64)
    constexpr int XS = 68;            // 64 rows + 4 pad (keeps 16B alignment)
    __shared__ __align__(16) float wl[32 * KO];
    __shared__ __align__(16) float xt[32 * XS];
    const int t = threadIdx.x;
    const int r0 = blockIdx.x * 64;
    const int tx = t % TPR, ty = t / TPR;
    float4 acc[RPT];
#pragma unroll
    for (int r = 0; r < RPT; ++r) acc[r] = make_float4(0.f, 0.f, 0.f, 0.f);

    for (int kb = 0; kb < KI; kb += 32) {
        __syncthreads();
#pragma unroll
        for (int i = t; i < 32 * KO / 4; i += 256)
            ((float4*)wl)[i] = ((const float4*)Wm)[kb * KO / 4 + i];
#pragma unroll
        for (int L = t; L < 512; L += 256) {
            int row = L >> 3, kq = L & 7;
            int gr = r0 + row;
            float4 v = make_float4(0.f, 0.f, 0.f, 0.f);
            if (gr < N) v = *(const float4*)(X + (size_t)gr * KI + kb + kq * 4);
            xt[(kq * 4 + 0) * XS + row] = v.x;
            xt[(kq * 4 + 1) * XS + row] = v.y;
            xt[(kq * 4 + 2) * XS + row] = v.z;
            xt[(kq * 4 + 3) * XS + row] = v.w;
        }
        __syncthreads();
#pragma unroll
        for (int k = 0; k < 32; ++k) {
            float4 wv = ((const float4*)wl)[k * TPR + tx];
            const float4* xp = (const float4*)(xt + k * XS + ty * RPT);
#pragma unroll
            for (int rq = 0; rq < RPT / 4; ++rq) {
                float4 xv = xp[rq];
                acc[rq*4+0].x += xv.x * wv.x; acc[rq*4+0].y += xv.x * wv.y;
                acc[rq*4+0].z += xv.x * wv.z; acc[rq*4+0].w += xv.x * wv.w;
                acc[rq*4+1].x += xv.y * wv.x; acc[rq*4+1].y += xv.y * wv.y;
                acc[rq*4+1].z += xv.y * wv.z; acc[rq*4+1].w += xv.y * wv.w;
                acc[rq*4+2].x += xv.z * wv.x; acc[rq*4+2].y += xv.z * wv.y;
                acc[rq*4+2].z += xv.z * wv.z; acc[rq*4+2].w += xv.z * wv.w;
                acc[rq*4+3].x += xv.w * wv.x; acc[rq*4+3].y += xv.w * wv.y;
                acc[rq*4+3].z += xv.w * wv.z; acc[rq*4+3].w += xv.w * wv.w;
            }
        }
    }
    float4 b4 = make_float4(0.f, 0.f, 0.f, 0.f);
    if (BIAS) b4 = ((const float4*)bias)[tx];
#pragma unroll
    for (int r = 0; r < RPT; ++r) {
        int gr = r0 + ty * RPT + r;
        if (gr < N) {
            float4 o = make_float4(acc[r].x + b4.x, acc[r].y + b4.y,
                                   acc[r].z + b4.z, acc[r].w + b4.w);
            if (RELU) {
                o.x = fmaxf(o.x, 0.f); o.y = fmaxf(o.y, 0.f);
                o.z = fmaxf(o.z, 0.f); o.w = fmaxf(o.w, 0.f);
            }
            *(float4*)(Y + (size_t)gr * KO + tx * 4) = o;
        }
    }
}

// ---- fused conv: Y[N,64] = ( relu(X[N,128] @ W1 + b1) ) @ W2, W2: [128,64] ----------
// R5 structure: 47.2 KB LDS (3 blocks/CU), conflict-free ht writes, VGPR ~72.
__global__ __launch_bounds__(256) void gemm23_kernel(const float* __restrict__ X,
                                                     const float* __restrict__ W1,
                                                     const float* __restrict__ b1,
                                                     const float* __restrict__ W2,
                                                     float* __restrict__ Y, int N) {
    __shared__ __align__(16) float wl[32 * 64];    // 8 KB: W1 16-k tiles / W2 32-k tiles
    __shared__ __align__(16) float xt[16 * 68];    // 4.35 KB: X^T [k][row+pad]
    __shared__ __align__(16) float ht[128 * 68];   // 34.8 KB: H^T [col][row+pad]
    const int t = threadIdx.x;
    const int r0 = blockIdx.x * 64;

    // ---- stage 1: H = relu(X @ W1 + b1) ----
    // mapping: tx in [0,32) -> rows {2tx, 2tx+1}; ty in [0,8) -> cols [16ty,16ty+16)
    const int tx = t & 31, ty = t >> 5;
    float acc[2][16];
#pragma unroll
    for (int r = 0; r < 2; ++r)
#pragma unroll
        for (int c = 0; c < 16; ++c) acc[r][c] = 0.f;

    for (int kb = 0; kb < 128; kb += 16) {
        __syncthreads();
        // W1 tile: rows kb..kb+16, all 128 cols = 512 float4
#pragma unroll
        for (int i = t; i < 512; i += 256)
            ((float4*)wl)[i] = ((const float4*)W1)[kb * 32 + i];
        // X tile transposed: 64 rows x 16 k  (row = t>>2, 4 f4-chunks of k per row)
        {
            int row = t >> 2, kq = t & 3;
            int gr = r0 + row;
            float4 v = make_float4(0.f, 0.f, 0.f, 0.f);
            if (gr < N) v = *(const float4*)(X + (size_t)gr * 128 + kb + kq * 4);
            xt[(kq * 4 + 0) * 68 + row] = v.x;
            xt[(kq * 4 + 1) * 68 + row] = v.y;
            xt[(kq * 4 + 2) * 68 + row] = v.z;
            xt[(kq * 4 + 3) * 68 + row] = v.w;
        }
        __syncthreads();
#pragma unroll
        for (int kk = 0; kk < 16; ++kk) {
            float2 xv = *(const float2*)(xt + kk * 68 + tx * 2);
            const float4* wp = (const float4*)(wl + kk * 128 + ty * 16);
#pragma unroll
            for (int cq = 0; cq < 4; ++cq) {
                float4 wv = wp[cq];
                acc[0][cq*4+0] += xv.x * wv.x; acc[0][cq*4+1] += xv.x * wv.y;
                acc[0][cq*4+2] += xv.x * wv.z; acc[0][cq*4+3] += xv.x * wv.w;
                acc[1][cq*4+0] += xv.y * wv.x; acc[1][cq*4+1] += xv.y * wv.y;
                acc[1][cq*4+2] += xv.y * wv.z; acc[1][cq*4+3] += xv.y * wv.w;
            }
        }
    }
    // bias + relu -> ht[col][row]; float2 per (col): banks 2tx -> 2-way (free)
    {
#pragma unroll
        for (int cq = 0; cq < 4; ++cq) {
            float4 b4 = ((const float4*)b1)[ty * 4 + cq];
            float bb[4] = { b4.x, b4.y, b4.z, b4.w };
#pragma unroll
            for (int j = 0; j < 4; ++j) {
                int col = ty * 16 + cq * 4 + j;
                float2 o;
                o.x = fmaxf(acc[0][cq*4+j] + bb[j], 0.f);
                o.y = fmaxf(acc[1][cq*4+j] + bb[j], 0.f);
                *(float2*)(ht + col * 68 + tx * 2) = o;
            }
        }
    }
    // ---- stage 2: Y = H @ W2 (128 -> 64) ----
    const int tx2 = t & 15, ty2 = t >> 4;          // 16 f4-cols, 16 groups x 4 rows
    float4 acc2[4];
#pragma unroll
    for (int r = 0; r < 4; ++r) acc2[r] = make_float4(0.f, 0.f, 0.f, 0.f);
    for (int kb = 0; kb < 4; ++kb) {
        __syncthreads();   // ht writes visible (first iter); wl readers done (later iters)
#pragma unroll
        for (int i = t; i < 512; i += 256)
            ((float4*)wl)[i] = ((const float4*)W2)[kb * 512 + i];
        __syncthreads();
#pragma unroll
        for (int k = 0; k < 32; ++k) {
            float4 wv = ((const float4*)wl)[k * 16 + tx2];
            float4 xv = *(const float4*)(ht + (kb * 32 + k) * 68 + ty2 * 4);
            acc2[0].x += xv.x * wv.x; acc2[0].y += xv.x * wv.y;
            acc2[0].z += xv.x * wv.z; acc2[0].w += xv.x * wv.w;
            acc2[1].x += xv.y * wv.x; acc2[1].y += xv.y * wv.y;
            acc2[1].z += xv.y * wv.z; acc2[1].w += xv.y * wv.w;
            acc2[2].x += xv.z * wv.x; acc2[2].y += xv.z * wv.y;
            acc2[2].z += xv.z * wv.z; acc2[2].w += xv.z * wv.w;
            acc2[3].x += xv.w * wv.x; acc2[3].y += xv.w * wv.y;
            acc2[3].z += xv.w * wv.z; acc2[3].w += xv.w * wv.w;
        }
    }
#pragma unroll
    for (int r = 0; r < 4; ++r) {
        int gr = r0 + ty2 * 4 + r;
        if (gr < N) *(float4*)(Y + (size_t)gr * 64 + tx2 * 4) = acc2[r];
    }
}

// ---------------- aggregation: out[n] = relu(x[n] + sum_{e:dst=n} x[src] + bias) -------
// 8-deep gather pipeline + 4-deep remainder, dual accumulators.
template <int VEC>  // float4s per row: 32 (width 128) or 16 (width 64)
__global__ __launch_bounds__(256) void agg_kernel(const float* __restrict__ x,
                                                  const int* __restrict__ rs,
                                                  const int* __restrict__ csr,
                                                  const float* __restrict__ bias,
                                                  float* __restrict__ out, int N) {
    const int NPB = 256 / VEC;
    const int t = threadIdx.x;
    const int node = blockIdx.x * NPB + t / VEC;
    const int c = t % VEC;
    if (node >= N) return;
    const float4* xb = (const float4*)x;
    float4 a0 = xb[(size_t)node * VEC + c];
    float4 a1 = make_float4(0.f, 0.f, 0.f, 0.f);
    int k = rs[node];
    const int s1 = rs[node + 1];
    for (; k + 8 <= s1; k += 8) {
        int i0 = csr[k], i1 = csr[k+1], i2 = csr[k+2], i3 = csr[k+3];
        int i4 = csr[k+4], i5 = csr[k+5], i6 = csr[k+6], i7 = csr[k+7];
        float4 v0 = xb[(size_t)i0 * VEC + c];
        float4 v1 = xb[(size_t)i1 * VEC + c];
        float4 v2 = xb[(size_t)i2 * VEC + c];
        float4 v3 = xb[(size_t)i3 * VEC + c];
        float4 v4 = xb[(size_t)i4 * VEC + c];
        float4 v5 = xb[(size_t)i5 * VEC + c];
        float4 v6 = xb[(size_t)i6 * VEC + c];
        float4 v7 = xb[(size_t)i7 * VEC + c];
        a0.x += v0.x; a0.y += v0.y; a0.z += v0.z; a0.w += v0.w;
        a1.x += v1.x; a1.y += v1.y; a1.z += v1.z; a1.w += v1.w;
        a0.x += v2.x; a0.y += v2.y; a0.z += v2.z; a0.w += v2.w;
        a1.x += v3.x; a1.y += v3.y; a1.z += v3.z; a1.w += v3.w;
        a0.x += v4.x; a0.y += v4.y; a0.z += v4.z; a0.w += v4.w;
        a1.x += v5.x; a1.y += v5.y; a1.z += v5.z; a1.w += v5.w;
        a0.x += v6.x; a0.y += v6.y; a0.z += v6.z; a0.w += v6.w;
        a1.x += v7.x; a1.y += v7.y; a1.z += v7.z; a1.w += v7.w;
    }
    if (k + 4 <= s1) {
        int i0 = csr[k], i1 = csr[k+1], i2 = csr[k+2], i3 = csr[k+3];
        float4 v0 = xb[(size_t)i0 * VEC + c];
        float4 v1 = xb[(size_t)i1 * VEC + c];
        float4 v2 = xb[(size_t)i2 * VEC + c];
        float4 v3 = xb[(size_t)i3 * VEC + c];
        a0.x += v0.x; a0.y += v0.y; a0.z += v0.z; a0.w += v0.w;
        a1.x += v1.x; a1.y += v1.y; a1.z += v1.z; a1.w += v1.w;
        a0.x += v2.x; a0.y += v2.y; a0.z += v2.z; a0.w += v2.w;
        a1.x += v3.x; a1.y += v3.y; a1.z += v3.z; a1.w += v3.w;
        k += 4;
    }
    for (; k < s1; ++k) {
        int i = csr[k];
        float4 v = xb[(size_t)i * VEC + c];
        a0.x += v.x; a0.y += v.y; a0.z += v.z; a0.w += v.w;
    }
    float4 b4 = ((const float4*)bias)[c];
    float4 o;
    o.x = fmaxf(a0.x + a1.x + b4.x, 0.f);
    o.y = fmaxf(a0.y + a1.y + b4.y, 0.f);
    o.z = fmaxf(a0.z + a1.z + b4.z, 0.f);
    o.w = fmaxf(a0.w + a1.w + b4.w, 0.f);
    ((float4*)out)[(size_t)node * VEC + c] = o;
}

// ---------------- scores: d(out1[n], out2[198]) via cdist formula, fp64 ----------------
__global__ __launch_bounds__(256) void scores_kernel(const float* __restrict__ out1,
                                                     const float* __restrict__ out2,
                                                     double* __restrict__ sc, int N) {
    const int t = threadIdx.x;
    const int node = blockIdx.x * 4 + (t >> 6);
    const int lane = t & 63;
    if (node >= N) return;
    float a = out1[(size_t)node * 64 + lane];
    float bv = out2[198 * 64 + lane];
    double na = (double)a * a;
    double nb = (double)bv * bv;
    double dd = (double)a * bv;
    for (int off = 32; off; off >>= 1) {
        na += __shfl_xor(na, off);
        nb += __shfl_xor(nb, off);
        dd += __shfl_xor(dd, off);
    }
    if (lane == 0) {
        double sq = na + nb - 2.0 * dd;
        sc[node] = (sq > 0.0) ? sqrt(sq) : 0.0;
    }
}

// ---------------- top-50 phase A: per-chunk top-50 into candidate list -----------------
__global__ __launch_bounds__(256) void topkA_kernel(const double* __restrict__ sc,
                                                    double* __restrict__ cv,
                                                    int* __restrict__ ci, int npg) {
    const int g = blockIdx.x / CPB, cb = blockIdx.x % CPB;
    const int chunk = (npg + CPB - 1) / CPB;
    const int base = cb * chunk;
    const int len = (npg - base < chunk) ? (npg - base) : chunk;
    const int t = threadIdx.x;
    __shared__ double lv[400];
    __shared__ double wvs[4];
    __shared__ int wss[4];
    const double* s = sc + (size_t)g * npg;
    for (int i = t; i < chunk; i += 256)
        lv[i] = (i < len) ? s[base + i] : -1.0e300;
    __syncthreads();
    const int ob = (g * CPB + cb) * 50;
    for (int r = 0; r < 50; ++r) {
        double bv = -1.0e300; int bs = 0x3fffffff;
        for (int i = t; i < chunk; i += 256) {
            double v = lv[i];
            if (v > bv || (v == bv && i < bs)) { bv = v; bs = i; }
        }
#pragma unroll
        for (int off = 32; off; off >>= 1) {
            double ov = __shfl_xor(bv, off);
            int os = __shfl_xor(bs, off);
            if (ov > bv || (ov == bv && os < bs)) { bv = ov; bs = os; }
        }
        if ((t & 63) == 0) { wvs[t >> 6] = bv; wss[t >> 6] = bs; }
        __syncthreads();
        if (t == 0) {
#pragma unroll
            for (int w = 1; w < 4; ++w)
                if (wvs[w] > bv || (wvs[w] == bv && wss[w] < bs)) { bv = wvs[w]; bs = wss[w]; }
            cv[ob + r] = bv;
            ci[ob + r] = base + bs;
            lv[bs] = -1.0e300;
        }
        __syncthreads();
    }
}

// ---------------- top-50 phase B: top-50 of CPB*50 candidates per graph ----------------
__global__ __launch_bounds__(256) void topkB_kernel(const double* __restrict__ cv,
                                                    const int* __restrict__ ci,
                                                    int* __restrict__ topk) {
    const int g = blockIdx.x, t = threadIdx.x;
    const int M = CPB * 50;   // 3200
    __shared__ double lv[CPB * 50];
    __shared__ int li[CPB * 50];
    __shared__ double wvs[4];
    __shared__ int wis[4], wss[4];
    for (int i = t; i < M; i += 256) {
        lv[i] = cv[(size_t)g * M + i];
        li[i] = ci[(size_t)g * M + i];
    }
    __syncthreads();
    for (int r = 0; r < 50; ++r) {
        double bv = -1.0e300; int bi = 0x3fffffff, bs = 0;
        for (int i = t; i < M; i += 256) {
            double v = lv[i]; int idx = li[i];
            if (v > bv || (v == bv && idx < bi)) { bv = v; bi = idx; bs = i; }
        }
#pragma unroll
        for (int off = 32; off; off >>= 1) {
            double ov = __shfl_xor(bv, off);
            int oi = __shfl_xor(bi, off);
            int os = __shfl_xor(bs, off);
            if (ov > bv || (ov == bv && oi < bi)) { bv = ov; bi = oi; bs = os; }
        }
        if ((t & 63) == 0) { wvs[t >> 6] = bv; wis[t >> 6] = bi; wss[t >> 6] = bs; }
        __syncthreads();
        if (t == 0) {
#pragma unroll
            for (int w = 1; w < 4; ++w)
                if (wvs[w] > bv || (wvs[w] == bv && wis[w] < bi)) {
                    bv = wvs[w]; bi = wis[w]; bs = wss[w];
                }
            topk[g * 50 + r] = bi;
            lv[bs] = -1.0e300;
        }
        __syncthreads();
    }
}

// ---------------- pooled rows: d(out1[sel], out2[j]) for 400 rows x 199 cols -----------
__global__ __launch_bounds__(256) void pooled_kernel(const float* __restrict__ out1,
                                                     const float* __restrict__ out2,
                                                     const int* __restrict__ topk,
                                                     float* __restrict__ pooled, int npg) {
    const int bk = blockIdx.x;           // 0..399
    const int g = bk / 50, kk = bk % 50;
    __shared__ float arow[64];
    const int t = threadIdx.x;
    const int node = g * npg + topk[g * 50 + kk];
    if (t < 64) arow[t] = out1[(size_t)node * 64 + t];
    __syncthreads();
    if (t < 199) {
        double na = 0.0, nb = 0.0, dd = 0.0;
        for (int k2 = 0; k2 < 64; ++k2) {
            double a = arow[k2];
            double b = out2[t * 64 + k2];
            na += a * a; nb += b * b; dd += a * b;
        }
        double sq = na + nb - 2.0 * dd;
        pooled[(size_t)g * 9950 + kk * 199 + t] = (float)((sq > 0.0) ? sqrt(sq) : 0.0);
    }
}

// ---------------- fc1 k-split: part[b,ks,f] = sum over chunk ks of p[i]*W[i,f] --------
__global__ __launch_bounds__(256) void fc1_partial_kernel(const float* __restrict__ pooled,
                                                          const float* __restrict__ W,
                                                          double* __restrict__ part) {
    const int b = blockIdx.x >> 6;        // / FKS
    const int ks = blockIdx.x & (FKS - 1);
    const int t = threadIdx.x;
    const int f = t & 127, half = t >> 7;
    const int C = (9950 + FKS - 1) / FKS; // 156
    const int i0 = ks * C;
    const int i1 = (i0 + C < 9950) ? (i0 + C) : 9950;
    const float* p = pooled + (size_t)b * 9950;
    double acc = 0.0;
    for (int i = i0 + half; i < i1; i += 2)
        acc += (double)p[i] * (double)W[(size_t)i * 128 + f];
    __shared__ double red[256];
    red[t] = acc; __syncthreads();
    if (half == 0)
        part[((size_t)b * FKS + ks) * 128 + f] = red[f] + red[128 + f];
}

__global__ __launch_bounds__(128) void fc1_reduce_kernel(const double* __restrict__ part,
                                                         const float* __restrict__ bias,
                                                         float* __restrict__ z1) {
    const int b = blockIdx.x, f = threadIdx.x;
    double acc = 0.0;
    for (int ks = 0; ks < FKS; ++ks)
        acc += part[((size_t)b * FKS + ks) * 128 + f];
    z1[b * 128 + f] = (float)(acc + (double)bias[f]);
}

// ---------------- head: LN+ReLU, fc2, LN+ReLU, fc3, sigmoid ---------------------------
__global__ __launch_bounds__(128) void head_kernel(const float* __restrict__ z1,
                                                   const float* __restrict__ g1,
                                                   const float* __restrict__ be1,
                                                   const float* __restrict__ W2,
                                                   const float* __restrict__ b2,
                                                   const float* __restrict__ g2,
                                                   const float* __restrict__ be2,
                                                   const float* __restrict__ W3,
                                                   const float* __restrict__ b3,
                                                   float* __restrict__ out) {
    const int b = blockIdx.x, t = threadIdx.x;
    __shared__ double red[128];
    __shared__ float shy[128];
    __shared__ float sh2[64];
    float z = z1[b * 128 + t];
    red[t] = z; __syncthreads();
    for (int off = 64; off; off >>= 1) { if (t < off) red[t] += red[t + off]; __syncthreads(); }
    double mu = red[0] / 128.0; __syncthreads();
    double dv = (double)z - mu;
    red[t] = dv * dv; __syncthreads();
    for (int off = 64; off; off >>= 1) { if (t < off) red[t] += red[t + off]; __syncthreads(); }
    double var = red[0] / 128.0; __syncthreads();
    float y = (float)(dv / sqrt(var + 1e-5)) * g1[t] + be1[t];
    shy[t] = fmaxf(y, 0.f); __syncthreads();
    double a2 = 0.0;
    if (t < 64) {
        for (int i = 0; i < 128; ++i) a2 += (double)shy[i] * (double)W2[i * 64 + t];
        a2 += (double)b2[t];
    }
    red[t] = (t < 64) ? a2 : 0.0; __syncthreads();
    for (int off = 64; off; off >>= 1) { if (t < off) red[t] += red[t + off]; __syncthreads(); }
    double mu2 = red[0] / 64.0; __syncthreads();
    double dv2 = a2 - mu2;
    red[t] = (t < 64) ? dv2 * dv2 : 0.0; __syncthreads();
    for (int off = 64; off; off >>= 1) { if (t < off) red[t] += red[t + off]; __syncthreads(); }
    double var2 = red[0] / 64.0; __syncthreads();
    if (t < 64) {
        float h2 = (float)(dv2 / sqrt(var2 + 1e-5)) * g2[t] + be2[t];
        sh2[t] = fmaxf(h2, 0.f);
    }
    __syncthreads();
    red[t] = (t < 64) ? (double)sh2[t] * (double)W3[t] : 0.0; __syncthreads();
    for (int off = 64; off; off >>= 1) { if (t < off) red[t] += red[t + off]; __syncthreads(); }
    if (t == 0) {
        double zf = red[0] + (double)b3[0];
        out[b] = (float)(1.0 / (1.0 + exp(-zf)));
    }
}

// ---------------------------------------------------------------------------
extern "C" void kernel_launch(void* const* d_in, const int* in_sizes, int n_in,
                              void* d_out, int out_size, void* d_ws, size_t ws_size,
                              hipStream_t stream) {
    (void)n_in; (void)out_size; (void)ws_size;
    const float* x1  = (const float*)d_in[0];
    const int*   ei1 = (const int*)d_in[1];
    const float* x2  = (const float*)d_in[3];
    const int*   ei2 = (const int*)d_in[4];
    const float* W1a = (const float*)d_in[5];
    const float* b1a = (const float*)d_in[6];
    const float* W1b = (const float*)d_in[7];
    const float* b1b = (const float*)d_in[8];
    const float* W2a = (const float*)d_in[9];
    const float* b2a = (const float*)d_in[10];
    const float* W2b = (const float*)d_in[11];
    const float* b2b = (const float*)d_in[12];
    const float* f1W = (const float*)d_in[13];
    const float* f1b = (const float*)d_in[14];
    const float* g1  = (const float*)d_in[15];
    const float* be1 = (const float*)d_in[16];
    const float* f2W = (const float*)d_in[17];
    const float* f2b = (const float*)d_in[18];
    const float* g2  = (const float*)d_in[19];
    const float* be2 = (const float*)d_in[20];
    const float* f3W = (const float*)d_in[21];
    const float* f3b = (const float*)d_in[22];
    float* out = (float*)d_out;

    const int n1 = in_sizes[0] / 128;     // 200000
    const int e1 = in_sizes[1] / 2;       // 2000000
    const int n2 = in_sizes[3] / 128;     // 199
    const int e2 = in_sizes[4] / 2;       // 3184
    const int npg = n1 / 8;               // 25000
    const int n  = n1 + n2;               // combined node count
    const int et = e1 + e2;

    // workspace carve-up
    char* p = (char*)d_ws;
    auto alloc = [&](size_t bytes) { char* r = p; p += (bytes + 255) & ~(size_t)255; return r; };
    float*  A    = (float*)alloc((size_t)n * 128 * 4);
    float*  Bb   = (float*)alloc((size_t)n * 128 * 4);
    double* sc   = (double*)alloc((size_t)n1 * 8);
    int*    rs   = (int*)alloc((size_t)(n + 1) * 4);    // counts -> row_start (in place)
    int*    cur  = (int*)alloc((size_t)(n + 1) * 4);
    int*    csr  = (int*)alloc((size_t)et * 4);
    int*    bsum = (int*)alloc(4096);
    double* cndv = (double*)alloc((size_t)8 * CPB * 50 * 8);
    int*    cndi = (int*)alloc((size_t)8 * CPB * 50 * 4);
    int*    tk   = (int*)alloc(8 * 50 * 4);
    float*  pld  = (float*)alloc((size_t)8 * 9950 * 4);
    double* f1p  = (double*)alloc((size_t)8 * FKS * 128 * 8);
    float*  z1   = (float*)alloc(8 * 128 * 4);

    const int* src1 = ei1;           const int* dst1 = ei1 + e1;
    const int* src2 = ei2;           const int* dst2 = ei2 + e2;

    // ---- combined CSR build (graph2 nodes appended after graph1's n1) ----
    hipMemsetAsync(rs, 0, (size_t)(n + 1) * 4, stream);
    hist_kernel<<<(e1 + 255) / 256, 256, 0, stream>>>(dst1, e1, rs, 0);
    hist_kernel<<<(e2 + 255) / 256, 256, 0, stream>>>(dst2, e2, rs, n1);
    int tot = n + 1, nch = (tot + 1023) / 1024;
    chunksum_kernel<<<nch, 256, 0, stream>>>(rs, tot, bsum);
    scanchunk_kernel<<<1, 256, 0, stream>>>(bsum, nch, nullptr, bsum, nullptr);
    scanchunk_kernel<<<nch, 256, 0, stream>>>(rs, tot, bsum, rs, cur);
    fill_kernel<<<(e1 + 255) / 256, 256, 0, stream>>>(src1, dst1, e1, cur, csr, 0);
    fill_kernel<<<(e2 + 255) / 256, 256, 0, stream>>>(src2, dst2, e2, cur, csr, n1);

    // ---- GIN on combined node set (shared weights) ----
    int gb  = (n + 63) / 64;
    int gb1 = (n1 + 63) / 64;
    int gb2 = (n2 + 63) / 64;
    gemm_kernel<128, 128, false, false><<<gb1, 256, 0, stream>>>(x1, W1a, nullptr, A, n1);
    gemm_kernel<128, 128, false, false><<<gb2, 256, 0, stream>>>(x2, W1a, nullptr,
                                                                 A + (size_t)n1 * 128, n2);
    agg_kernel<32><<<(n + 7) / 8, 256, 0, stream>>>(A, rs, csr, b1a, Bb, n);
    gemm23_kernel<<<gb, 256, 0, stream>>>(Bb, W1b, b1b, W2a, A, n);      // A = h@W2a [n,64]
    agg_kernel<16><<<(n + 15) / 16, 256, 0, stream>>>(A, rs, csr, b2a, Bb, n);
    gemm_kernel<64, 64, true, true><<<gb, 256, 0, stream>>>(Bb, W2b, b2b, A, n);  // out = A

    const float* out1 = A;
    const float* o2   = A + (size_t)n1 * 64;

    // ---- scores -> two-phase top-50 per graph -> pooled rows ----
    scores_kernel<<<(n1 + 3) / 4, 256, 0, stream>>>(out1, o2, sc, n1);
    topkA_kernel<<<8 * CPB, 256, 0, stream>>>(sc, cndv, cndi, npg);
    topkB_kernel<<<8, 256, 0, stream>>>(cndv, cndi, tk);
    pooled_kernel<<<400, 256, 0, stream>>>(out1, o2, tk, pld, npg);

    // ---- head ----
    fc1_partial_kernel<<<8 * FKS, 256, 0, stream>>>(pld, f1W, f1p);
    fc1_reduce_kernel<<<8, 128, 0, stream>>>(f1p, f1b, z1);
    head_kernel<<<8, 128, 0, stream>>>(z1, g1, be1, f2W, f2b, g2, be2, f3W, f3b, out);
}